// Round 11
// baseline (839.248 us; speedup 1.0000x reference)
//
#include <hip/hip_runtime.h>
#include <hip/hip_fp16.h>

typedef _Float16 f16;
typedef _Float16 half8 __attribute__((ext_vector_type(8)));
typedef _Float16 half4 __attribute__((ext_vector_type(4)));
typedef float f32x4 __attribute__((ext_vector_type(4)));

static __device__ __forceinline__ void fence_lds(){
  asm volatile("s_waitcnt lgkmcnt(0)" ::: "memory");
  __builtin_amdgcn_sched_barrier(0);
}

// ---------------- K0: W1 (128x128), W2 (128x288) -> transposed f16 ----------------
__global__ void k0_convert(const float* __restrict__ W1, const float* __restrict__ W2,
                           f16* __restrict__ W1T, f16* __restrict__ W2T){
  int o = blockIdx.x*256 + threadIdx.x;   // 208*256 = 53248 = 16384 + 36864 exactly
  if (o < 128*128){
    int j = o >> 7, i = o & 127;          // W1T[j][i] = W1[i][j]
    W1T[o] = (f16)W1[i*128 + j];
  } else {
    int o2 = o - 128*128;
    int n = o2 >> 7, i = o2 & 127;        // W2T[n][i] = W2[i][n]
    W2T[o2] = (f16)W2[i*288 + n];
  }
}

struct ERegs { f32x4 a, b, xa, xb, m0, m1, m2, m3; };

static __device__ __forceinline__ ERegs load_edge(
    const float* __restrict__ x, const int* __restrict__ eidx,
    const float* __restrict__ efa, const float* __restrict__ efb,
    const float* __restrict__ em, int e, int E, int l){
  ERegs r;
  const size_t eb = (size_t)e * 256;
  const int ia = eidx[e], ib = eidx[E + e];
  r.a  = *(const f32x4*)(efa + eb + l*4);
  r.b  = *(const f32x4*)(efb + eb + l*4);
  r.xa = *(const f32x4*)(x + (size_t)ia*256 + l*4);
  r.xb = *(const f32x4*)(x + (size_t)ib*256 + l*4);
  const size_t mb = (size_t)e * 1024;
  r.m0 = *(const f32x4*)(em + mb +   0 + l*4);
  r.m1 = *(const f32x4*)(em + mb + 256 + l*4);
  r.m2 = *(const f32x4*)(em + mb + 512 + l*4);
  r.m3 = *(const f32x4*)(em + mb + 768 + l*4);
  return r;
}

// ---------------- wave-independent fused kernel, 256-thread packaging ----------------
// block = 256 threads = 4 INDEPENDENT wave-pipelines; ZERO __syncthreads.
// Wave w owns edges blockIdx*16 + w*4 .. +3 end-to-end in its own LDS arena.
// Per-wave MLP: A-rows replicated via (n16&3) so D-row 4q+j == edge j in every
// q-group (all lanes hold all results); LDS writebacks split by (ct&3)==q.
//
// Per-wave arena [4800 f16] = 9600 B, time-phased (f16 idx within arena):
//   phase1: scratch Mb/AXT/BXT/MBXT [0,3200); h0 rows sH [4256,4800)  (disjoint)
//   GEMM1:  reads sH; h1 overwrites sH (after fence)
//   GEMM2:  reads sH; writes sRw f32[4][292] at [0,2336)   (scratch dead)
//   phase3: reads sRw; LHSst [2336,3616) + RT [3616,4256); sO f32[32][17]
//           aliases LHSst [2336,3424) after MFMA operand reads drain.
// Block LDS = 4*9600 = 38400 B -> 4 blocks/CU by LDS; launch_bounds(256,3)
// (VGPR cap 168; do NOT force 4 — R7/R8 spill pathology).
__global__ __launch_bounds__(256, 3) void k_wave(
    const float* __restrict__ x, const int* __restrict__ eidx,
    const float* __restrict__ efa, const float* __restrict__ efb,
    const float* __restrict__ em,
    const f16* __restrict__ W1T, const f16* __restrict__ W2T,
    const float* __restrict__ b1, const float* __restrict__ lng,
    const float* __restrict__ lnb, const float* __restrict__ b2,
    float* __restrict__ outA, float* __restrict__ outB, int E)
{
  __shared__ f16 sArena[4*4800];

  const int tid = threadIdx.x;
  const int l = tid & 63, w = tid >> 6;
  const int q = l >> 4, n16 = l & 15;
  const int e0 = blockIdx.x * 16 + w * 4;

  f16* sWk = sArena + w*4800;

  f16*   Mb    = sWk;            // [32][40]
  f16*   AXT   = Mb + 1280;      // [16][40]
  f16*   BXT   = AXT + 640;      // [16][40]
  f16*   MBXT  = BXT + 640;      // [16][40], scratch ends at 3200
  float* sRw   = (float*)sWk;    // [4][292] f32 (GEMM2 out), [0,2336) f16-units
  f16*   LHSst = sWk + 2336;     // [32][40]
  f16*   RT    = sWk + 3616;     // [16][40]
  float* sO    = (float*)(sWk + 2336);  // [32][17] f32, aliases LHSst
  f16*   sH    = sWk + 4256;     // [4][136] h rows (stride 272B, 16B-aligned)

  half4 hA[4], hXa[4], hB[4], hXb[4];

  // ======== phase 1: per-edge overlaps -> sH rows (h0) ========
  ERegs cur = load_edge(x, eidx, efa, efb, em, e0, E, l);
  #pragma unroll
  for (int i = 0; i < 4; ++i){
    ERegs nxt;
    if (i < 3) nxt = load_edge(x, eidx, efa, efb, em, e0 + i + 1, E, l);

    {
      int d = l >> 1, cb = (l & 1)*4;
      half4 ta, txa, tb, txb;
      #pragma unroll
      for (int j = 0; j < 4; ++j){
        int c = cb + j;
        f16 va  = (f16)cur.a[j],  vxa = (f16)cur.xa[j];
        f16 vb  = (f16)cur.b[j],  vxb = (f16)cur.xb[j];
        AXT[c*40 + d]     = va;   AXT[(8+c)*40 + d] = vxa;
        BXT[c*40 + d]     = vb;   BXT[(8+c)*40 + d] = vxb;
        ta[j] = va; txa[j] = vxa; tb[j] = vb; txb[j] = vxb;
      }
      hA[i] = ta; hXa[i] = txa; hB[i] = tb; hXb[i] = txb;
      int r0 = l >> 3, c0 = (l & 7)*4;
      f16* p0 = Mb + ( 0 + r0)*40 + c0;
      p0[0]=(f16)cur.m0[0]; p0[1]=(f16)cur.m0[1]; p0[2]=(f16)cur.m0[2]; p0[3]=(f16)cur.m0[3];
      f16* p1 = Mb + ( 8 + r0)*40 + c0;
      p1[0]=(f16)cur.m1[0]; p1[1]=(f16)cur.m1[1]; p1[2]=(f16)cur.m1[2]; p1[3]=(f16)cur.m1[3];
      f16* p2 = Mb + (16 + r0)*40 + c0;
      p2[0]=(f16)cur.m2[0]; p2[1]=(f16)cur.m2[1]; p2[2]=(f16)cur.m2[2]; p2[3]=(f16)cur.m2[3];
      f16* p3 = Mb + (24 + r0)*40 + c0;
      p3[0]=(f16)cur.m3[0]; p3[1]=(f16)cur.m3[1]; p3[2]=(f16)cur.m3[2]; p3[3]=(f16)cur.m3[3];
    }
    fence_lds();

    // mfma1: [MB|MXb](32x16) = M(32x32) @ [B|Xb](32x16)
    half8 bF  = *(half8*)(BXT + n16*40 + q*8);
    half8 aF0 = *(half8*)(Mb  + n16*40      + q*8);
    half8 aF1 = *(half8*)(Mb  + (16+n16)*40 + q*8);
    f32x4 z = {0.f,0.f,0.f,0.f};
    f32x4 d0 = __builtin_amdgcn_mfma_f32_16x16x32_f16(aF0, bF, z, 0,0,0);
    f32x4 d1 = __builtin_amdgcn_mfma_f32_16x16x32_f16(aF1, bF, z, 0,0,0);
    {
      f16* p0 = MBXT + n16*40 + q*4;
      p0[0]=(f16)d0[0]; p0[1]=(f16)d0[1]; p0[2]=(f16)d0[2]; p0[3]=(f16)d0[3];
      f16* p1 = MBXT + n16*40 + 16 + q*4;
      p1[0]=(f16)d1[0]; p1[1]=(f16)d1[1]; p1[2]=(f16)d1[2]; p1[3]=(f16)d1[3];
    }
    fence_lds();

    // mfma2: [eo|no](16x16) = [A|Xa]^T(16x32) @ [MB|MXb](32x16)
    half8 aF2 = *(half8*)(AXT  + n16*40 + q*8);
    half8 bF2 = *(half8*)(MBXT + n16*40 + q*8);
    f32x4 d2 = __builtin_amdgcn_mfma_f32_16x16x32_f16(aF2, bF2, z, 0,0,0);

    // h0 row i -> sH[i][*] (plain layout, stride 136)
    if (q < 2 && n16 < 8){
      #pragma unroll
      for (int j=0;j<4;++j) sH[i*136 + (4*q+j)*8 + n16] = (f16)d2[j];
    }
    if (q >= 2 && n16 >= 8){
      #pragma unroll
      for (int j=0;j<4;++j) sH[i*136 + 64 + (4*(q-2)+j)*8 + (n16-8)] = (f16)d2[j];
    }
    if (i < 3) cur = nxt;
    fence_lds();
  }

  // ======== GEMM1 (per-wave): 4 edges x 128, A-rows replicated ========
  half8 aFk[4];
  #pragma unroll
  for (int ks=0; ks<4; ++ks)
    aFk[ks] = *(const half8*)(sH + (n16&3)*136 + ks*32 + q*8);

  float sv[8][4];
  float sAcc[4]  = {0.f,0.f,0.f,0.f};
  float sqAcc[4] = {0.f,0.f,0.f,0.f};
  #pragma unroll
  for (int ct=0; ct<8; ++ct){
    f32x4 a1 = {0.f,0.f,0.f,0.f};
    #pragma unroll
    for (int ks=0; ks<4; ++ks){
      half8 bF = *(const half8*)(W1T + (ct*16 + n16)*128 + ks*32 + q*8);
      a1 = __builtin_amdgcn_mfma_f32_16x16x32_f16(aFk[ks], bF, a1, 0,0,0);
    }
    float bb = b1[ct*16 + n16];
    #pragma unroll
    for (int j=0; j<4; ++j){
      float v = a1[j] + bb;                 // D-row 4q+j == edge j (replicated over q)
      float s = v / (1.f + __expf(-v));
      sv[ct][j] = s;
      sAcc[j] += s; sqAcc[j] += s*s;
    }
  }
  // LN stats: reduce over n16 within each 16-lane group (all q groups identical)
  #pragma unroll
  for (int m=1; m<16; m<<=1){
    #pragma unroll
    for (int j=0; j<4; ++j){
      sAcc[j]  += __shfl_xor(sAcc[j],  m, 64);
      sqAcc[j] += __shfl_xor(sqAcc[j], m, 64);
    }
  }
  float mu[4], rs[4];
  #pragma unroll
  for (int j=0; j<4; ++j){
    float m_ = sAcc[j] * (1.f/128.f);
    mu[j] = m_;
    rs[j] = rsqrtf(sqAcc[j] * (1.f/128.f) - m_*m_ + 1e-5f);
  }
  fence_lds();                  // h0 reads drained before overwrite
  // h1 -> sH (each q-group writes its ct subset)
  #pragma unroll
  for (int ct=0; ct<8; ++ct){
    if ((ct & 3) == q){
      float g = lng[ct*16 + n16], bb = lnb[ct*16 + n16];
      #pragma unroll
      for (int j=0; j<4; ++j){
        float hn = (sv[ct][j] - mu[j])*rs[j]*g + bb;
        sH[j*136 + ct*16 + n16] = (f16)hn;
      }
    }
  }
  fence_lds();

  // ======== GEMM2 (per-wave): 4 edges x 288 -> sRw ========
  half8 aFh[4];
  #pragma unroll
  for (int ks=0; ks<4; ++ks)
    aFh[ks] = *(const half8*)(sH + (n16&3)*136 + ks*32 + q*8);
  #pragma unroll
  for (int ct=0; ct<18; ++ct){
    f32x4 a2 = {0.f,0.f,0.f,0.f};
    #pragma unroll
    for (int ks=0; ks<4; ++ks){
      half8 bF = *(const half8*)(W2T + (ct*16 + n16)*128 + ks*32 + q*8);
      a2 = __builtin_amdgcn_mfma_f32_16x16x32_f16(aFh[ks], bF, a2, 0,0,0);
    }
    if ((ct & 3) == q){
      float bb = b2[ct*16 + n16];
      #pragma unroll
      for (int j=0; j<4; ++j)
        sRw[j*292 + ct*16 + n16] = a2[j] + bb;   // scratch dead; sH untouched
    }
  }
  fence_lds();

  // ======== phase 3: normalize weights, output matmuls (4 edges) ========
  f32x4 w4v[4]; float ssq[4];
  #pragma unroll
  for (int i=0;i<4;++i){
    w4v[i] = *(const f32x4*)(sRw + i*292 + l*4);
    ssq[i] = w4v[i][0]*w4v[i][0] + w4v[i][1]*w4v[i][1]
           + w4v[i][2]*w4v[i][2] + w4v[i][3]*w4v[i][3];
  }
  #pragma unroll
  for (int m=1;m<16;m<<=1){
    #pragma unroll
    for (int i=0;i<4;++i) ssq[i] += __shfl_xor(ssq[i], m, 64);
  }
  float rn[4];
  #pragma unroll
  for (int i=0;i<4;++i) rn[i] = 1.f / (sqrtf(ssq[i]) + 1e-6f);

  #pragma unroll
  for (int i = 0; i < 4; ++i){
    const int e = e0 + i;
    {
      uint32_t* z32 = (uint32_t*)RT;
      z32[l] = 0u; z32[l+64] = 0u; z32[l+128] = 0u; z32[l+192] = 0u; z32[l+256] = 0u;
    }
    const int mm = l >> 4;
    const int kk = n16 >> 1;
    #pragma unroll
    for (int j=0;j<4;++j){
      int c = (l & 1)*4 + j;
      float f = sRw[i*292 + 256 + mm*8 + c];
      f16 val = (f16)(w4v[i][j] * rn[i] * f * 0.5f);
      int nOut = c + (mm & 1)*8;
      int rk   = kk + ((mm & 1) << 4) + ((mm >> 1) << 3);
      RT[nOut*40 + rk] = val;
    }
    {
      int d = l >> 1, cb = (l & 1)*4;
      *(half4*)(LHSst + d*40 + cb)      = hA[i];
      *(half4*)(LHSst + d*40 + 8 + cb)  = hXa[i];
      *(half4*)(LHSst + d*40 + 16 + cb) = hB[i];
      *(half4*)(LHSst + d*40 + 24 + cb) = hXb[i];
    }
    fence_lds();
    half8 bF  = *(const half8*)(RT + n16*40 + q*8);
    half8 aF0 = *(const half8*)(LHSst + n16*40 + q*8);
    half8 aF1 = *(const half8*)(LHSst + (16 + n16)*40 + q*8);
    fence_lds();   // LHSst reads drained -> bytes reusable as sO
    f32x4 z = {0.f,0.f,0.f,0.f};
    f32x4 Dv0 = __builtin_amdgcn_mfma_f32_16x16x32_f16(aF0, bF, z, 0,0,0);
    f32x4 Dv1 = __builtin_amdgcn_mfma_f32_16x16x32_f16(aF1, bF, z, 0,0,0);
    #pragma unroll
    for (int j=0;j<4;++j){
      sO[(      4*q + j)*17 + n16] = Dv0[j];
      sO[(16 +  4*q + j)*17 + n16] = Dv1[j];
    }
    fence_lds();
    {
      const size_t eb = (size_t)e * 256;
      int d = l >> 1, cb = (l & 1)*4;
      f32x4 va, vb;
      #pragma unroll
      for (int j=0;j<4;++j){
        va[j] = sO[d*17 + cb + j];
        vb[j] = sO[d*17 + 8 + cb + j];
      }
      *(f32x4*)(outA + eb + l*4) = va;
      *(f32x4*)(outB + eb + l*4) = vb;
    }
    fence_lds();
  }
}

extern "C" void kernel_launch(void* const* d_in, const int* in_sizes, int n_in,
                              void* d_out, int out_size, void* d_ws, size_t ws_size,
                              hipStream_t stream) {
  const float* x   = (const float*)d_in[0];
  const int*   ei  = (const int*)  d_in[1];
  const float* efa = (const float*)d_in[2];
  const float* efb = (const float*)d_in[3];
  const float* em  = (const float*)d_in[4];
  const float* W1  = (const float*)d_in[5];
  const float* b1  = (const float*)d_in[6];
  const float* lng = (const float*)d_in[7];
  const float* lnb = (const float*)d_in[8];
  const float* W2  = (const float*)d_in[9];
  const float* b2  = (const float*)d_in[10];
  const int E = in_sizes[1] / 2;

  float* outA = (float*)d_out;
  float* outB = outA + (size_t)E*256;
  f16* W1T = (f16*)d_ws;             // 128*128 f16
  f16* W2T = W1T + 128*128;          // 288*128 f16

  k0_convert<<<208, 256, 0, stream>>>(W1, W2, W1T, W2T);
  k_wave<<<E/16, 256, 0, stream>>>(x, ei, efa, efb, em, W1T, W2T,
                                   b1, lng, lnb, b2, outA, outB, E);
}

// Round 12
// 503.246 us; speedup vs baseline: 1.6677x; 1.6677x over previous
//
#include <hip/hip_runtime.h>
#include <hip/hip_fp16.h>

typedef _Float16 f16;
typedef _Float16 half8 __attribute__((ext_vector_type(8)));
typedef _Float16 half4 __attribute__((ext_vector_type(4)));
typedef float f32x4 __attribute__((ext_vector_type(4)));

static __device__ __forceinline__ void fence_lds(){
  asm volatile("s_waitcnt lgkmcnt(0)" ::: "memory");
  __builtin_amdgcn_sched_barrier(0);
}

// ---------------- K0: W1 (128x128), W2 (128x288) -> transposed f16 ----------------
__global__ void k0_convert(const float* __restrict__ W1, const float* __restrict__ W2,
                           f16* __restrict__ W1T, f16* __restrict__ W2T){
  int o = blockIdx.x*256 + threadIdx.x;   // 208*256 = 53248 = 16384 + 36864 exactly
  if (o < 128*128){
    int j = o >> 7, i = o & 127;          // W1T[j][i] = W1[i][j]
    W1T[o] = (f16)W1[i*128 + j];
  } else {
    int o2 = o - 128*128;
    int n = o2 >> 7, i = o2 & 127;        // W2T[n][i] = W2[i][n]
    W2T[o2] = (f16)W2[i*288 + n];
  }
}

struct ERegs { f32x4 a, b, xa, xb, m0, m1, m2, m3; };

static __device__ __forceinline__ ERegs load_edge(
    const float* __restrict__ x, const int* __restrict__ eidx,
    const float* __restrict__ efa, const float* __restrict__ efb,
    const float* __restrict__ em, int e, int E, int l){
  ERegs r;
  const size_t eb = (size_t)e * 256;
  const int ia = eidx[e], ib = eidx[E + e];
  r.a  = *(const f32x4*)(efa + eb + l*4);
  r.b  = *(const f32x4*)(efb + eb + l*4);
  r.xa = *(const f32x4*)(x + (size_t)ia*256 + l*4);
  r.xb = *(const f32x4*)(x + (size_t)ib*256 + l*4);
  const size_t mb = (size_t)e * 1024;
  r.m0 = *(const f32x4*)(em + mb +   0 + l*4);
  r.m1 = *(const f32x4*)(em + mb + 256 + l*4);
  r.m2 = *(const f32x4*)(em + mb + 512 + l*4);
  r.m3 = *(const f32x4*)(em + mb + 768 + l*4);
  return r;
}

// ---------------- fused: overlaps + MLP + normalize + output matmuls ----------------
// block = 256 thr (4 waves), 16 edges; wave w owns edges w*4..w*4+3 end-to-end.
//
// Single LDS arena sWk[17024 f16] = 34048 B.
// launch_bounds(256,3): do NOT force 4 — the 4-bound forces VGPR=64 -> spills
// -> +600MB HBM traffic (R7/R8, confirmed by R9's VGPR=84/WRITE=400MB).
// Phase 3 uses DIRECT strided stores (R5-proven, WRITE=400MB exactly); the sO
// LDS staging variant (R9) cost 2 fences/edge + 1.5x bank conflicts for zero
// traffic benefit.
// Time-phased layout (f16 indices; b<N> = Nth __syncthreads):
//   phase1 (before b1): scratch wave w at [w*3200, +3200) = Mb/AXT/BXT/MBXT; sH0 [12800,14848)
//   GEMM1  (b1..b2):    reads sH0; sStat f32 [0,256) written after GEMM1 (scratch dead since b1)
//   LN     (b2..b3):    reads sStat; writes sH1 [9344,11392) (disjoint from sStat & sH0)
//   GEMM2  (b3..b4):    reads sH1 [18688,22784)B; writes sR f32 [0,18688)B  (disjoint)
//   phase3 (after b4):  reads sR; per-wave pw at [9344 + w*1920, +1920) = LHSst[32][40]+RT[16][40]
__global__ __launch_bounds__(256, 3) void k_fused(
    const float* __restrict__ x, const int* __restrict__ eidx,
    const float* __restrict__ efa, const float* __restrict__ efb,
    const float* __restrict__ em,
    const f16* __restrict__ W1T, const f16* __restrict__ W2T,
    const float* __restrict__ b1, const float* __restrict__ lng,
    const float* __restrict__ lnb, const float* __restrict__ b2,
    float* __restrict__ outA, float* outB, int E)
{
  __shared__ f16 sWk[17024];

  const int tid = threadIdx.x;
  const int l = tid & 63, w = tid >> 6, q = l >> 4, n16 = l & 15;
  const int e0 = blockIdx.x * 16;

  f16*   sH0   = sWk + 12800;    // [16][128] h0, swizzled chunks
  f16*   sH1   = sWk + 9344;     // [16][128] h1, swizzled chunks
  float* sStat = (float*)sWk;    // [128]
  float* sR    = (float*)sWk;    // [16][292] f32

  f16* Mb   = sWk + w*3200;     // [32][40]
  f16* AXT  = Mb + 1280;        // [16][40]  rows: c(A) 0..7, c(Xa) 8..15 ; cols d
  f16* BXT  = AXT + 640;        // [16][40]  rows: c(B) 0..7, c(Xb) 8..15
  f16* MBXT = BXT + 640;        // [16][40]  rows: n of [MB|MXb], cols i

  // per-edge feature fragments held in registers (statically indexed; loops unrolled)
  half4 hA[4], hXa[4], hB[4], hXb[4];

  // ======== phase 1: overlaps -> sH0 (h0) ========
  ERegs cur = load_edge(x, eidx, efa, efb, em, e0 + w*4, E, l);
  #pragma unroll
  for (int i = 0; i < 4; ++i){
    const int le = w*4 + i;
    ERegs nxt;
    if (i < 3) nxt = load_edge(x, eidx, efa, efb, em, e0 + le + 1, E, l);

    // stage transposed tiles; keep direct-layout fragments in registers
    {
      int d = l >> 1, cb = (l & 1)*4;
      half4 ta, txa, tb, txb;
      #pragma unroll
      for (int j = 0; j < 4; ++j){
        int c = cb + j;
        f16 va  = (f16)cur.a[j],  vxa = (f16)cur.xa[j];
        f16 vb  = (f16)cur.b[j],  vxb = (f16)cur.xb[j];
        AXT[c*40 + d]     = va;   AXT[(8+c)*40 + d] = vxa;
        BXT[c*40 + d]     = vb;   BXT[(8+c)*40 + d] = vxb;
        ta[j] = va; txa[j] = vxa; tb[j] = vb; txb[j] = vxb;
      }
      hA[i] = ta; hXa[i] = txa; hB[i] = tb; hXb[i] = txb;
      int r0 = l >> 3, c0 = (l & 7)*4;
      f16* p0 = Mb + ( 0 + r0)*40 + c0;
      p0[0]=(f16)cur.m0[0]; p0[1]=(f16)cur.m0[1]; p0[2]=(f16)cur.m0[2]; p0[3]=(f16)cur.m0[3];
      f16* p1 = Mb + ( 8 + r0)*40 + c0;
      p1[0]=(f16)cur.m1[0]; p1[1]=(f16)cur.m1[1]; p1[2]=(f16)cur.m1[2]; p1[3]=(f16)cur.m1[3];
      f16* p2 = Mb + (16 + r0)*40 + c0;
      p2[0]=(f16)cur.m2[0]; p2[1]=(f16)cur.m2[1]; p2[2]=(f16)cur.m2[2]; p2[3]=(f16)cur.m2[3];
      f16* p3 = Mb + (24 + r0)*40 + c0;
      p3[0]=(f16)cur.m3[0]; p3[1]=(f16)cur.m3[1]; p3[2]=(f16)cur.m3[2]; p3[3]=(f16)cur.m3[3];
    }
    fence_lds();

    // mfma1: [MB|MXb](32x16) = M(32x32) @ [B|Xb](32x16)
    half8 bF  = *(half8*)(BXT + n16*40 + q*8);
    half8 aF0 = *(half8*)(Mb  + n16*40      + q*8);
    half8 aF1 = *(half8*)(Mb  + (16+n16)*40 + q*8);
    f32x4 z = {0.f,0.f,0.f,0.f};
    f32x4 d0 = __builtin_amdgcn_mfma_f32_16x16x32_f16(aF0, bF, z, 0,0,0);
    f32x4 d1 = __builtin_amdgcn_mfma_f32_16x16x32_f16(aF1, bF, z, 0,0,0);
    {
      f16* p0 = MBXT + n16*40 + q*4;
      p0[0]=(f16)d0[0]; p0[1]=(f16)d0[1]; p0[2]=(f16)d0[2]; p0[3]=(f16)d0[3];
      f16* p1 = MBXT + n16*40 + 16 + q*4;
      p1[0]=(f16)d1[0]; p1[1]=(f16)d1[1]; p1[2]=(f16)d1[2]; p1[3]=(f16)d1[3];
    }
    fence_lds();

    // mfma2: [eo|no](16x16) = [A|Xa]^T(16x32) @ [MB|MXb](32x16)
    half8 aF2 = *(half8*)(AXT  + n16*40 + q*8);
    half8 bF2 = *(half8*)(MBXT + n16*40 + q*8);
    f32x4 d2 = __builtin_amdgcn_mfma_f32_16x16x32_f16(aF2, bF2, z, 0,0,0);

    // h0 row -> sH0[le], swizzled in chunks of 8: chunk ^= (row&7)
    if (q < 2 && n16 < 8){
      #pragma unroll
      for (int j=0;j<4;++j){
        int ch = 4*q + j;                              // i = ch*8 + n16  (eo -> h[0:64])
        sH0[le*128 + ((ch ^ (le & 7))*8) + n16] = (f16)d2[j];
      }
    }
    if (q >= 2 && n16 >= 8){
      #pragma unroll
      for (int j=0;j<4;++j){
        int ch = 8 + 4*(q-2) + j;                      // no -> h[64:128]
        sH0[le*128 + ((ch ^ (le & 7))*8) + (n16-8)] = (f16)d2[j];
      }
    }
    if (i < 3) cur = nxt;
    fence_lds();
  }
  __syncthreads();                                     // b1: scratch dead from here

  // ======== GEMM1: (16x128) @ W1(128x128); wave w -> col tiles 2w, 2w+1 ========
  f32x4 acc[2] = {{0,0,0,0},{0,0,0,0}};
  #pragma unroll
  for (int ks = 0; ks < 4; ++ks){
    half8 aF = *(const half8*)(sH0 + n16*128 + (((ks*4 + q) ^ (n16 & 7))*8));
    #pragma unroll
    for (int c2 = 0; c2 < 2; ++c2){
      int ct = 2*w + c2;
      half8 bF = *(const half8*)(W1T + (size_t)(ct*16 + n16)*128 + ks*32 + q*8);
      acc[c2] = __builtin_amdgcn_mfma_f32_16x16x32_f16(aF, bF, acc[c2], 0,0,0);
    }
  }
  // bias + silu
  float sv[2][4];
  #pragma unroll
  for (int c2=0;c2<2;++c2)
    #pragma unroll
    for (int j=0;j<4;++j){
      int col = (2*w + c2)*16 + n16;
      float v = acc[c2][j] + b1[col];
      sv[c2][j] = v / (1.f + __expf(-v));
    }
  // LN stats
  #pragma unroll
  for (int j=0;j<4;++j){
    float s  = sv[0][j] + sv[1][j];
    float sq = sv[0][j]*sv[0][j] + sv[1][j]*sv[1][j];
    #pragma unroll
    for (int m=1;m<16;m<<=1){ s += __shfl_xor(s, m, 64); sq += __shfl_xor(sq, m, 64); }
    if (n16 == 0){ sStat[(w*16 + 4*q + j)*2] = s; sStat[(w*16 + 4*q + j)*2 + 1] = sq; }
  }
  __syncthreads();                                     // b2
  float mu[4], rs[4];
  #pragma unroll
  for (int j=0;j<4;++j){
    int row = 4*q + j;
    float s=0.f, sq=0.f;
    #pragma unroll
    for (int w2=0;w2<4;++w2){ s += sStat[(w2*16+row)*2]; sq += sStat[(w2*16+row)*2+1]; }
    float m_ = s * (1.f/128.f);
    mu[j] = m_;
    rs[j] = rsqrtf(sq * (1.f/128.f) - m_*m_ + 1e-5f);
  }
  // h1 -> sH1 (disjoint from sStat [0,512)B and sH0 [25600,29696)B)
  #pragma unroll
  for (int c2=0;c2<2;++c2)
    #pragma unroll
    for (int j=0;j<4;++j){
      int col = (2*w + c2)*16 + n16;
      int row = 4*q + j;
      float hn = (sv[c2][j] - mu[j])*rs[j]*lng[col] + lnb[col];
      sH1[row*128 + (((col>>3) ^ (row&7))*8) + (col&7)] = (f16)hn;
    }
  __syncthreads();                                     // b3

  // ======== GEMM2: (16x128) @ W2(128x288) -> sR f32 [0,18688)B (disjoint from sH1 reads) ========
  f32x4 acc2[5] = {{0,0,0,0},{0,0,0,0},{0,0,0,0},{0,0,0,0},{0,0,0,0}};
  #pragma unroll
  for (int ks=0;ks<4;++ks){
    half8 aF = *(const half8*)(sH1 + n16*128 + (((ks*4 + q) ^ (n16 & 7))*8));
    #pragma unroll
    for (int t=0;t<5;++t){
      int ct = w + 4*t;
      if (ct < 18){
        half8 bF = *(const half8*)(W2T + (size_t)(ct*16 + n16)*128 + ks*32 + q*8);
        acc2[t] = __builtin_amdgcn_mfma_f32_16x16x32_f16(aF, bF, acc2[t], 0,0,0);
      }
    }
  }
  #pragma unroll
  for (int t=0;t<5;++t){
    int ct = w + 4*t;
    if (ct < 18){
      #pragma unroll
      for (int j=0;j<4;++j){
        int col = ct*16 + n16, row = 4*q + j;
        sR[row*292 + col] = acc2[t][j] + b2[col];
      }
    }
  }
  __syncthreads();                                     // b4: sH0/sH1 dead from here

  // ======== phase 3: normalize weights, output matmuls; wave w -> its 4 edges ========
  f16* pw    = sWk + 9344 + w*1920;   // after sR's 18688 B (= 9344 f16)
  f16* LHSst = pw;                    // [32][40]
  f16* RT    = pw + 1280;             // [16][40] RHS^T

  // batched: all 4 edges' weight rows + interleaved shfl reduction trees (ILP)
  f32x4 w4v[4]; float ssq[4];
  #pragma unroll
  for (int i=0;i<4;++i){
    w4v[i] = *(const f32x4*)(sR + (w*4+i)*292 + l*4);
    ssq[i] = w4v[i][0]*w4v[i][0] + w4v[i][1]*w4v[i][1]
           + w4v[i][2]*w4v[i][2] + w4v[i][3]*w4v[i][3];
  }
  #pragma unroll
  for (int m=1;m<16;m<<=1){
    #pragma unroll
    for (int i=0;i<4;++i) ssq[i] += __shfl_xor(ssq[i], m, 64);
  }
  float rn[4];
  #pragma unroll
  for (int i=0;i<4;++i) rn[i] = 1.f / (sqrtf(ssq[i]) + 1e-6f);

  #pragma unroll
  for (int i = 0; i < 4; ++i){
    const int le = w*4 + i;
    const int e  = e0 + le;
    // zero RT: 640 f16 = 320 dwords = 5*64
    {
      uint32_t* z32 = (uint32_t*)RT;
      z32[l] = 0u; z32[l+64] = 0u; z32[l+128] = 0u; z32[l+192] = 0u; z32[l+256] = 0u;
    }
    const int mm = l >> 4;
    const int kk = n16 >> 1;
    #pragma unroll
    for (int j=0;j<4;++j){
      int c = (l & 1)*4 + j;
      float f = sR[le*292 + 256 + mm*8 + c];
      f16 val = (f16)(w4v[i][j] * rn[i] * f * 0.5f);
      int nOut = c + (mm & 1)*8;
      int rk   = kk + ((mm & 1) << 4) + ((mm >> 1) << 3);
      RT[nOut*40 + rk] = val;
    }
    // stage LHS from held registers: row d, cols 0..7 A, 8..15 Xa, 16..23 B, 24..31 Xb
    {
      int d = l >> 1, cb = (l & 1)*4;
      *(half4*)(LHSst + d*40 + cb)      = hA[i];
      *(half4*)(LHSst + d*40 + 8 + cb)  = hXa[i];
      *(half4*)(LHSst + d*40 + 16 + cb) = hB[i];
      *(half4*)(LHSst + d*40 + 24 + cb) = hXb[i];
    }
    fence_lds();
    // [out_a|out_b](32x16) = LHS(32x32) @ RHS(32x16); direct strided stores (R5-proven)
    half8 bF = *(const half8*)(RT + n16*40 + q*8);
    f32x4 z = {0.f,0.f,0.f,0.f};
    const size_t eb = (size_t)e * 256;
    float* obase = (n16 < 8) ? (outA + eb + n16) : (outB + eb + n16 - 8);
    #pragma unroll
    for (int rt=0;rt<2;++rt){
      half8 aF = *(const half8*)(LHSst + (rt*16 + n16)*40 + q*8);
      f32x4 Dv = __builtin_amdgcn_mfma_f32_16x16x32_f16(aF, bF, z, 0,0,0);
      #pragma unroll
      for (int j=0;j<4;++j){
        int dR = rt*16 + 4*q + j;
        obase[dR*8] = Dv[j];
      }
    }
    fence_lds();
  }
}

extern "C" void kernel_launch(void* const* d_in, const int* in_sizes, int n_in,
                              void* d_out, int out_size, void* d_ws, size_t ws_size,
                              hipStream_t stream) {
  const float* x   = (const float*)d_in[0];
  const int*   ei  = (const int*)  d_in[1];
  const float* efa = (const float*)d_in[2];
  const float* efb = (const float*)d_in[3];
  const float* em  = (const float*)d_in[4];
  const float* W1  = (const float*)d_in[5];
  const float* b1  = (const float*)d_in[6];
  const float* lng = (const float*)d_in[7];
  const float* lnb = (const float*)d_in[8];
  const float* W2  = (const float*)d_in[9];
  const float* b2  = (const float*)d_in[10];
  const int E = in_sizes[1] / 2;

  float* outA = (float*)d_out;
  float* outB = outA + (size_t)E*256;
  f16* W1T = (f16*)d_ws;             // 128*128 f16
  f16* W2T = W1T + 128*128;          // 288*128 f16

  k0_convert<<<208, 256, 0, stream>>>(W1, W2, W1T, W2T);
  k_fused<<<E/16, 256, 0, stream>>>(x, ei, efa, efb, em, W1T, W2T,
                                    b1, lng, lnb, b2, outA, outB, E);
}

// Round 13
// 434.921 us; speedup vs baseline: 1.9297x; 1.1571x over previous
//
#include <hip/hip_runtime.h>
#include <hip/hip_fp16.h>

typedef _Float16 f16;
typedef _Float16 half8 __attribute__((ext_vector_type(8)));
typedef _Float16 half4 __attribute__((ext_vector_type(4)));
typedef float f32x4 __attribute__((ext_vector_type(4)));

static __device__ __forceinline__ void fence_lds(){
  asm volatile("s_waitcnt lgkmcnt(0)" ::: "memory");
  __builtin_amdgcn_sched_barrier(0);
}

// ---------------- K0: W1 (128x128), W2 (128x288) -> transposed f16 ----------------
__global__ void k0_convert(const float* __restrict__ W1, const float* __restrict__ W2,
                           f16* __restrict__ W1T, f16* __restrict__ W2T){
  int o = blockIdx.x*256 + threadIdx.x;   // 208*256 = 53248 = 16384 + 36864 exactly
  if (o < 128*128){
    int j = o >> 7, i = o & 127;          // W1T[j][i] = W1[i][j]
    W1T[o] = (f16)W1[i*128 + j];
  } else {
    int o2 = o - 128*128;
    int n = o2 >> 7, i = o2 & 127;        // W2T[n][i] = W2[i][n]
    W2T[o2] = (f16)W2[i*288 + n];
  }
}

struct ERegs { f32x4 a, b, xa, xb, m0, m1, m2, m3; };

static __device__ __forceinline__ ERegs load_edge(
    const float* __restrict__ x, const int* __restrict__ eidx,
    const float* __restrict__ efa, const float* __restrict__ efb,
    const float* __restrict__ em, int e, int E, int l){
  ERegs r;
  const size_t eb = (size_t)e * 256;
  const int ia = eidx[e], ib = eidx[E + e];
  r.a  = *(const f32x4*)(efa + eb + l*4);
  r.b  = *(const f32x4*)(efb + eb + l*4);
  r.xa = *(const f32x4*)(x + (size_t)ia*256 + l*4);
  r.xb = *(const f32x4*)(x + (size_t)ib*256 + l*4);
  const size_t mb = (size_t)e * 1024;
  r.m0 = *(const f32x4*)(em + mb +   0 + l*4);
  r.m1 = *(const f32x4*)(em + mb + 256 + l*4);
  r.m2 = *(const f32x4*)(em + mb + 512 + l*4);
  r.m3 = *(const f32x4*)(em + mb + 768 + l*4);
  return r;
}

// ---------------- fused: overlaps + MLP + normalize + output matmuls ----------------
// R5 structure (best verified: 477us wall): separate buffers, 42752 B LDS,
// launch_bounds(256,3), direct strided stores, per-edge phase-3 reductions.
// R13 single change: DEPTH-2 edge prefetch in phase 1 (edge i+2's loads issued
// at iter i) — covers ~2 loop bodies of HBM latency instead of 1.
// Do NOT force occupancy 4: VGPR=64 pathology (R7/R8) causes spills (+600MB HBM).
__global__ __launch_bounds__(256, 3) void k_fused(
    const float* __restrict__ x, const int* __restrict__ eidx,
    const float* __restrict__ efa, const float* __restrict__ efb,
    const float* __restrict__ em,
    const f16* __restrict__ W1T, const f16* __restrict__ W2T,
    const float* __restrict__ b1, const float* __restrict__ lng,
    const float* __restrict__ lnb, const float* __restrict__ b2,
    float* __restrict__ outA, float* outB, int E)
{
  __shared__ f16   sWk[17024];
  __shared__ f16   sH0[16*128];     // h0 (swizzled chunks)
  __shared__ f16   sH1[16*128];     // h1 (swizzled chunks)
  __shared__ float sStat[128];

  const int tid = threadIdx.x;
  const int l = tid & 63, w = tid >> 6, q = l >> 4, n16 = l & 15;
  const int e0 = blockIdx.x * 16;

  f16* Mb   = sWk + w*3200;     // [32][40]
  f16* AXT  = Mb + 1280;        // [16][40]  rows: c(A) 0..7, c(Xa) 8..15 ; cols d
  f16* BXT  = AXT + 640;        // [16][40]  rows: c(B) 0..7, c(Xb) 8..15
  f16* MBXT = BXT + 640;        // [16][40]  rows: n of [MB|MXb], cols i

  // per-edge feature fragments held in registers (statically indexed; loops unrolled)
  half4 hA[4], hXa[4], hB[4], hXb[4];

  // ======== phase 1: overlaps -> sH0 (h0), depth-2 prefetch ========
  ERegs buf0 = load_edge(x, eidx, efa, efb, em, e0 + w*4,     E, l);
  ERegs buf1 = load_edge(x, eidx, efa, efb, em, e0 + w*4 + 1, E, l);
  #pragma unroll
  for (int i = 0; i < 4; ++i){
    const int le = w*4 + i;
    ERegs nxt2;
    if (i < 2) nxt2 = load_edge(x, eidx, efa, efb, em, e0 + le + 2, E, l);

    // stage transposed tiles from buf0; keep direct-layout fragments in registers
    {
      int d = l >> 1, cb = (l & 1)*4;
      half4 ta, txa, tb, txb;
      #pragma unroll
      for (int j = 0; j < 4; ++j){
        int c = cb + j;
        f16 va  = (f16)buf0.a[j],  vxa = (f16)buf0.xa[j];
        f16 vb  = (f16)buf0.b[j],  vxb = (f16)buf0.xb[j];
        AXT[c*40 + d]     = va;   AXT[(8+c)*40 + d] = vxa;
        BXT[c*40 + d]     = vb;   BXT[(8+c)*40 + d] = vxb;
        ta[j] = va; txa[j] = vxa; tb[j] = vb; txb[j] = vxb;
      }
      hA[i] = ta; hXa[i] = txa; hB[i] = tb; hXb[i] = txb;
      int r0 = l >> 3, c0 = (l & 7)*4;
      f16* p0 = Mb + ( 0 + r0)*40 + c0;
      p0[0]=(f16)buf0.m0[0]; p0[1]=(f16)buf0.m0[1]; p0[2]=(f16)buf0.m0[2]; p0[3]=(f16)buf0.m0[3];
      f16* p1 = Mb + ( 8 + r0)*40 + c0;
      p1[0]=(f16)buf0.m1[0]; p1[1]=(f16)buf0.m1[1]; p1[2]=(f16)buf0.m1[2]; p1[3]=(f16)buf0.m1[3];
      f16* p2 = Mb + (16 + r0)*40 + c0;
      p2[0]=(f16)buf0.m2[0]; p2[1]=(f16)buf0.m2[1]; p2[2]=(f16)buf0.m2[2]; p2[3]=(f16)buf0.m2[3];
      f16* p3 = Mb + (24 + r0)*40 + c0;
      p3[0]=(f16)buf0.m3[0]; p3[1]=(f16)buf0.m3[1]; p3[2]=(f16)buf0.m3[2]; p3[3]=(f16)buf0.m3[3];
    }
    fence_lds();

    // mfma1: [MB|MXb](32x16) = M(32x32) @ [B|Xb](32x16)
    half8 bF  = *(half8*)(BXT + n16*40 + q*8);
    half8 aF0 = *(half8*)(Mb  + n16*40      + q*8);
    half8 aF1 = *(half8*)(Mb  + (16+n16)*40 + q*8);
    f32x4 z = {0.f,0.f,0.f,0.f};
    f32x4 d0 = __builtin_amdgcn_mfma_f32_16x16x32_f16(aF0, bF, z, 0,0,0);
    f32x4 d1 = __builtin_amdgcn_mfma_f32_16x16x32_f16(aF1, bF, z, 0,0,0);
    {
      f16* p0 = MBXT + n16*40 + q*4;
      p0[0]=(f16)d0[0]; p0[1]=(f16)d0[1]; p0[2]=(f16)d0[2]; p0[3]=(f16)d0[3];
      f16* p1 = MBXT + n16*40 + 16 + q*4;
      p1[0]=(f16)d1[0]; p1[1]=(f16)d1[1]; p1[2]=(f16)d1[2]; p1[3]=(f16)d1[3];
    }
    fence_lds();

    // mfma2: [eo|no](16x16) = [A|Xa]^T(16x32) @ [MB|MXb](32x16)
    half8 aF2 = *(half8*)(AXT  + n16*40 + q*8);
    half8 bF2 = *(half8*)(MBXT + n16*40 + q*8);
    f32x4 d2 = __builtin_amdgcn_mfma_f32_16x16x32_f16(aF2, bF2, z, 0,0,0);

    // h0 row -> sH0[le], swizzled in chunks of 8: chunk ^= (row&7)
    if (q < 2 && n16 < 8){
      #pragma unroll
      for (int j=0;j<4;++j){
        int ch = 4*q + j;                              // i = ch*8 + n16  (eo -> h[0:64])
        sH0[le*128 + ((ch ^ (le & 7))*8) + n16] = (f16)d2[j];
      }
    }
    if (q >= 2 && n16 >= 8){
      #pragma unroll
      for (int j=0;j<4;++j){
        int ch = 8 + 4*(q-2) + j;                      // no -> h[64:128]
        sH0[le*128 + ((ch ^ (le & 7))*8) + (n16-8)] = (f16)d2[j];
      }
    }
    buf0 = buf1;
    if (i < 2) buf1 = nxt2;
    fence_lds();
  }
  __syncthreads();

  // ======== GEMM1: (16x128) @ W1(128x128); wave w -> col tiles 2w, 2w+1 ========
  f32x4 acc[2] = {{0,0,0,0},{0,0,0,0}};
  #pragma unroll
  for (int ks = 0; ks < 4; ++ks){
    half8 aF = *(const half8*)(sH0 + n16*128 + (((ks*4 + q) ^ (n16 & 7))*8));
    #pragma unroll
    for (int c2 = 0; c2 < 2; ++c2){
      int ct = 2*w + c2;
      half8 bF = *(const half8*)(W1T + (size_t)(ct*16 + n16)*128 + ks*32 + q*8);
      acc[c2] = __builtin_amdgcn_mfma_f32_16x16x32_f16(aF, bF, acc[c2], 0,0,0);
    }
  }
  // bias + silu
  float sv[2][4];
  #pragma unroll
  for (int c2=0;c2<2;++c2)
    #pragma unroll
    for (int j=0;j<4;++j){
      int col = (2*w + c2)*16 + n16;
      float v = acc[c2][j] + b1[col];
      sv[c2][j] = v / (1.f + __expf(-v));
    }
  // LN stats
  #pragma unroll
  for (int j=0;j<4;++j){
    float s  = sv[0][j] + sv[1][j];
    float sq = sv[0][j]*sv[0][j] + sv[1][j]*sv[1][j];
    #pragma unroll
    for (int m=1;m<16;m<<=1){ s += __shfl_xor(s, m, 64); sq += __shfl_xor(sq, m, 64); }
    if (n16 == 0){ sStat[(w*16 + 4*q + j)*2] = s; sStat[(w*16 + 4*q + j)*2 + 1] = sq; }
  }
  __syncthreads();
  float mu[4], rs[4];
  #pragma unroll
  for (int j=0;j<4;++j){
    int row = 4*q + j;
    float s=0.f, sq=0.f;
    #pragma unroll
    for (int w2=0;w2<4;++w2){ s += sStat[(w2*16+row)*2]; sq += sStat[(w2*16+row)*2+1]; }
    float m_ = s * (1.f/128.f);
    mu[j] = m_;
    rs[j] = rsqrtf(sq * (1.f/128.f) - m_*m_ + 1e-5f);
  }
  // h1 -> sH1
  #pragma unroll
  for (int c2=0;c2<2;++c2)
    #pragma unroll
    for (int j=0;j<4;++j){
      int col = (2*w + c2)*16 + n16;
      int row = 4*q + j;
      float hn = (sv[c2][j] - mu[j])*rs[j]*lng[col] + lnb[col];
      sH1[row*128 + (((col>>3) ^ (row&7))*8) + (col&7)] = (f16)hn;
    }
  __syncthreads();

  // ======== GEMM2: (16x128) @ W2(128x288) -> sR (f32, aliases dead phase-1 scratch) ========
  float* sR = (float*)sWk;         // [16][292] f32 = 18688 B
  f32x4 acc2[5] = {{0,0,0,0},{0,0,0,0},{0,0,0,0},{0,0,0,0},{0,0,0,0}};
  #pragma unroll
  for (int ks=0;ks<4;++ks){
    half8 aF = *(const half8*)(sH1 + n16*128 + (((ks*4 + q) ^ (n16 & 7))*8));
    #pragma unroll
    for (int t=0;t<5;++t){
      int ct = w + 4*t;
      if (ct < 18){
        half8 bF = *(const half8*)(W2T + (size_t)(ct*16 + n16)*128 + ks*32 + q*8);
        acc2[t] = __builtin_amdgcn_mfma_f32_16x16x32_f16(aF, bF, acc2[t], 0,0,0);
      }
    }
  }
  #pragma unroll
  for (int t=0;t<5;++t){
    int ct = w + 4*t;
    if (ct < 18){
      #pragma unroll
      for (int j=0;j<4;++j){
        int col = ct*16 + n16, row = 4*q + j;
        sR[row*292 + col] = acc2[t][j] + b2[col];
      }
    }
  }
  __syncthreads();

  // ======== phase 3: normalize weights, output matmuls; wave w -> its 4 edges ========
  f16* pw    = sWk + 9344 + w*1920;   // after sR's 18688 B (= 9344 f16)
  f16* LHSst = pw;                    // [32][40]
  f16* RT    = pw + 1280;             // [16][40] RHS^T
  #pragma unroll
  for (int i = 0; i < 4; ++i){
    const int le = w*4 + i;
    const int e  = e0 + le;
    // weights: lane l holds mlp_res[l*4 .. l*4+3] = matrix mm=l>>4, flat (n16*4+j)
    f32x4 w4 = *(const f32x4*)(sR + le*292 + l*4);
    float ssq = w4[0]*w4[0] + w4[1]*w4[1] + w4[2]*w4[2] + w4[3]*w4[3];
    #pragma unroll
    for (int m=1;m<16;m<<=1) ssq += __shfl_xor(ssq, m, 64);
    float rn = 1.f / (sqrtf(ssq) + 1e-6f);
    // zero RT: 640 f16 = 320 dwords = 5*64
    {
      uint32_t* z32 = (uint32_t*)RT;
      z32[l] = 0u; z32[l+64] = 0u; z32[l+128] = 0u; z32[l+192] = 0u; z32[l+256] = 0u;
    }
    const int mm = l >> 4;
    const int kk = n16 >> 1;
    #pragma unroll
    for (int j=0;j<4;++j){
      int c = (l & 1)*4 + j;
      float f = sR[le*292 + 256 + mm*8 + c];
      f16 val = (f16)(w4[j] * rn * f * 0.5f);
      int nOut = c + (mm & 1)*8;
      int rk   = kk + ((mm & 1) << 4) + ((mm >> 1) << 3);
      RT[nOut*40 + rk] = val;
    }
    // stage LHS from held registers: row d, cols 0..7 A, 8..15 Xa, 16..23 B, 24..31 Xb
    {
      int d = l >> 1, cb = (l & 1)*4;
      *(half4*)(LHSst + d*40 + cb)      = hA[i];
      *(half4*)(LHSst + d*40 + 8 + cb)  = hXa[i];
      *(half4*)(LHSst + d*40 + 16 + cb) = hB[i];
      *(half4*)(LHSst + d*40 + 24 + cb) = hXb[i];
    }
    fence_lds();
    // [out_a|out_b](32x16) = LHS(32x32) @ RHS(32x16); direct strided stores
    half8 bF = *(const half8*)(RT + n16*40 + q*8);
    f32x4 z = {0.f,0.f,0.f,0.f};
    const size_t eb = (size_t)e * 256;
    float* obase = (n16 < 8) ? (outA + eb + n16) : (outB + eb + n16 - 8);
    #pragma unroll
    for (int rt=0;rt<2;++rt){
      half8 aF = *(const half8*)(LHSst + (rt*16 + n16)*40 + q*8);
      f32x4 Dv = __builtin_amdgcn_mfma_f32_16x16x32_f16(aF, bF, z, 0,0,0);
      #pragma unroll
      for (int j=0;j<4;++j){
        int dR = rt*16 + 4*q + j;
        obase[dR*8] = Dv[j];
      }
    }
    fence_lds();
  }
}

extern "C" void kernel_launch(void* const* d_in, const int* in_sizes, int n_in,
                              void* d_out, int out_size, void* d_ws, size_t ws_size,
                              hipStream_t stream) {
  const float* x   = (const float*)d_in[0];
  const int*   ei  = (const int*)  d_in[1];
  const float* efa = (const float*)d_in[2];
  const float* efb = (const float*)d_in[3];
  const float* em  = (const float*)d_in[4];
  const float* W1  = (const float*)d_in[5];
  const float* b1  = (const float*)d_in[6];
  const float* lng = (const float*)d_in[7];
  const float* lnb = (const float*)d_in[8];
  const float* W2  = (const float*)d_in[9];
  const float* b2  = (const float*)d_in[10];
  const int E = in_sizes[1] / 2;

  float* outA = (float*)d_out;
  float* outB = outA + (size_t)E*256;
  f16* W1T = (f16*)d_ws;             // 128*128 f16
  f16* W2T = W1T + 128*128;          // 288*128 f16

  k0_convert<<<208, 256, 0, stream>>>(W1, W2, W1T, W2T);
  k_fused<<<E/16, 256, 0, stream>>>(x, ei, efa, efb, em, W1T, W2T,
                                    b1, lng, lnb, b2, outA, outB, E);
}

// Round 14
// 418.825 us; speedup vs baseline: 2.0038x; 1.0384x over previous
//
#include <hip/hip_runtime.h>
#include <hip/hip_fp16.h>

typedef _Float16 f16;
typedef _Float16 half8 __attribute__((ext_vector_type(8)));
typedef _Float16 half4 __attribute__((ext_vector_type(4)));
typedef float f32x4 __attribute__((ext_vector_type(4)));
typedef int   int4v __attribute__((ext_vector_type(4)));

static __device__ __forceinline__ void fence_lds(){
  asm volatile("s_waitcnt lgkmcnt(0)" ::: "memory");
  __builtin_amdgcn_sched_barrier(0);
}

// ---------------- K0: W1 (128x128), W2 (128x288) -> transposed f16 ----------------
__global__ void k0_convert(const float* __restrict__ W1, const float* __restrict__ W2,
                           f16* __restrict__ W1T, f16* __restrict__ W2T){
  int o = blockIdx.x*256 + threadIdx.x;   // 208*256 = 53248 = 16384 + 36864 exactly
  if (o < 128*128){
    int j = o >> 7, i = o & 127;          // W1T[j][i] = W1[i][j]
    W1T[o] = (f16)W1[i*128 + j];
  } else {
    int o2 = o - 128*128;
    int n = o2 >> 7, i = o2 & 127;        // W2T[n][i] = W2[i][n]
    W2T[o2] = (f16)W2[i*288 + n];
  }
}

struct ERegs { f32x4 a, b, xa, xb, m0, m1, m2, m3; };

// indices passed in (hoisted): no dependent eidx->gather chain inside
static __device__ __forceinline__ ERegs load_edge_i(
    const float* __restrict__ x,
    const float* __restrict__ efa, const float* __restrict__ efb,
    const float* __restrict__ em, int e, int ia, int ib, int l){
  ERegs r;
  const size_t eb = (size_t)e * 256;
  r.a  = *(const f32x4*)(efa + eb + l*4);
  r.b  = *(const f32x4*)(efb + eb + l*4);
  r.xa = *(const f32x4*)(x + (size_t)ia*256 + l*4);
  r.xb = *(const f32x4*)(x + (size_t)ib*256 + l*4);
  const size_t mb = (size_t)e * 1024;
  r.m0 = *(const f32x4*)(em + mb +   0 + l*4);
  r.m1 = *(const f32x4*)(em + mb + 256 + l*4);
  r.m2 = *(const f32x4*)(em + mb + 512 + l*4);
  r.m3 = *(const f32x4*)(em + mb + 768 + l*4);
  return r;
}

// ---------------- fused: overlaps + MLP + normalize + output matmuls ----------------
// R13 base (best verified: 435us wall) + R14 single conceptual change:
// flatten the phase-1 load pipeline — (a) hoist all 4 eidx pairs as two int4
// loads (kills the eidx->x-gather dependent chain), (b) prefetch depth 3.
// Do NOT force occupancy 4: VGPR=64 pathology (R7/R8) causes spills (+600MB HBM).
// Spill tripwire: WRITE_SIZE must stay 400MB.
__global__ __launch_bounds__(256, 3) void k_fused(
    const float* __restrict__ x, const int* __restrict__ eidx,
    const float* __restrict__ efa, const float* __restrict__ efb,
    const float* __restrict__ em,
    const f16* __restrict__ W1T, const f16* __restrict__ W2T,
    const float* __restrict__ b1, const float* __restrict__ lng,
    const float* __restrict__ lnb, const float* __restrict__ b2,
    float* __restrict__ outA, float* outB, int E)
{
  __shared__ f16   sWk[17024];
  __shared__ f16   sH0[16*128];     // h0 (swizzled chunks)
  __shared__ f16   sH1[16*128];     // h1 (swizzled chunks)
  __shared__ float sStat[128];

  const int tid = threadIdx.x;
  const int l = tid & 63, w = tid >> 6, q = l >> 4, n16 = l & 15;
  const int e0 = blockIdx.x * 16;

  f16* Mb   = sWk + w*3200;     // [32][40]
  f16* AXT  = Mb + 1280;        // [16][40]  rows: c(A) 0..7, c(Xa) 8..15 ; cols d
  f16* BXT  = AXT + 640;        // [16][40]  rows: c(B) 0..7, c(Xb) 8..15
  f16* MBXT = BXT + 640;        // [16][40]  rows: n of [MB|MXb], cols i

  // per-edge feature fragments held in registers (statically indexed; loops unrolled)
  half4 hA[4], hXa[4], hB[4], hXb[4];

  // ======== phase 1: overlaps -> sH0 (h0); hoisted eidx + depth-3 prefetch ========
  const int ew = e0 + w*4;
  int4v iav = *(const int4v*)(eidx + ew);        // 4 contiguous src indices
  int4v ibv = *(const int4v*)(eidx + E + ew);    // 4 contiguous dst indices

  ERegs buf0 = load_edge_i(x, efa, efb, em, ew,     iav[0], ibv[0], l);
  ERegs buf1 = load_edge_i(x, efa, efb, em, ew + 1, iav[1], ibv[1], l);
  ERegs buf2 = load_edge_i(x, efa, efb, em, ew + 2, iav[2], ibv[2], l);
  #pragma unroll
  for (int i = 0; i < 4; ++i){
    const int le = w*4 + i;
    ERegs nxt3;
    if (i < 1) nxt3 = load_edge_i(x, efa, efb, em, ew + 3, iav[3], ibv[3], l);

    // stage transposed tiles from buf0; keep direct-layout fragments in registers
    {
      int d = l >> 1, cb = (l & 1)*4;
      half4 ta, txa, tb, txb;
      #pragma unroll
      for (int j = 0; j < 4; ++j){
        int c = cb + j;
        f16 va  = (f16)buf0.a[j],  vxa = (f16)buf0.xa[j];
        f16 vb  = (f16)buf0.b[j],  vxb = (f16)buf0.xb[j];
        AXT[c*40 + d]     = va;   AXT[(8+c)*40 + d] = vxa;
        BXT[c*40 + d]     = vb;   BXT[(8+c)*40 + d] = vxb;
        ta[j] = va; txa[j] = vxa; tb[j] = vb; txb[j] = vxb;
      }
      hA[i] = ta; hXa[i] = txa; hB[i] = tb; hXb[i] = txb;
      int r0 = l >> 3, c0 = (l & 7)*4;
      f16* p0 = Mb + ( 0 + r0)*40 + c0;
      p0[0]=(f16)buf0.m0[0]; p0[1]=(f16)buf0.m0[1]; p0[2]=(f16)buf0.m0[2]; p0[3]=(f16)buf0.m0[3];
      f16* p1 = Mb + ( 8 + r0)*40 + c0;
      p1[0]=(f16)buf0.m1[0]; p1[1]=(f16)buf0.m1[1]; p1[2]=(f16)buf0.m1[2]; p1[3]=(f16)buf0.m1[3];
      f16* p2 = Mb + (16 + r0)*40 + c0;
      p2[0]=(f16)buf0.m2[0]; p2[1]=(f16)buf0.m2[1]; p2[2]=(f16)buf0.m2[2]; p2[3]=(f16)buf0.m2[3];
      f16* p3 = Mb + (24 + r0)*40 + c0;
      p3[0]=(f16)buf0.m3[0]; p3[1]=(f16)buf0.m3[1]; p3[2]=(f16)buf0.m3[2]; p3[3]=(f16)buf0.m3[3];
    }
    fence_lds();

    // mfma1: [MB|MXb](32x16) = M(32x32) @ [B|Xb](32x16)
    half8 bF  = *(half8*)(BXT + n16*40 + q*8);
    half8 aF0 = *(half8*)(Mb  + n16*40      + q*8);
    half8 aF1 = *(half8*)(Mb  + (16+n16)*40 + q*8);
    f32x4 z = {0.f,0.f,0.f,0.f};
    f32x4 d0 = __builtin_amdgcn_mfma_f32_16x16x32_f16(aF0, bF, z, 0,0,0);
    f32x4 d1 = __builtin_amdgcn_mfma_f32_16x16x32_f16(aF1, bF, z, 0,0,0);
    {
      f16* p0 = MBXT + n16*40 + q*4;
      p0[0]=(f16)d0[0]; p0[1]=(f16)d0[1]; p0[2]=(f16)d0[2]; p0[3]=(f16)d0[3];
      f16* p1 = MBXT + n16*40 + 16 + q*4;
      p1[0]=(f16)d1[0]; p1[1]=(f16)d1[1]; p1[2]=(f16)d1[2]; p1[3]=(f16)d1[3];
    }
    fence_lds();

    // mfma2: [eo|no](16x16) = [A|Xa]^T(16x32) @ [MB|MXb](32x16)
    half8 aF2 = *(half8*)(AXT  + n16*40 + q*8);
    half8 bF2 = *(half8*)(MBXT + n16*40 + q*8);
    f32x4 d2 = __builtin_amdgcn_mfma_f32_16x16x32_f16(aF2, bF2, z, 0,0,0);

    // h0 row -> sH0[le], swizzled in chunks of 8: chunk ^= (row&7)
    if (q < 2 && n16 < 8){
      #pragma unroll
      for (int j=0;j<4;++j){
        int ch = 4*q + j;                              // i = ch*8 + n16  (eo -> h[0:64])
        sH0[le*128 + ((ch ^ (le & 7))*8) + n16] = (f16)d2[j];
      }
    }
    if (q >= 2 && n16 >= 8){
      #pragma unroll
      for (int j=0;j<4;++j){
        int ch = 8 + 4*(q-2) + j;                      // no -> h[64:128]
        sH0[le*128 + ((ch ^ (le & 7))*8) + (n16-8)] = (f16)d2[j];
      }
    }
    buf0 = buf1; buf1 = buf2;
    if (i < 1) buf2 = nxt3;
    fence_lds();
  }
  __syncthreads();

  // ======== GEMM1: (16x128) @ W1(128x128); wave w -> col tiles 2w, 2w+1 ========
  f32x4 acc[2] = {{0,0,0,0},{0,0,0,0}};
  #pragma unroll
  for (int ks = 0; ks < 4; ++ks){
    half8 aF = *(const half8*)(sH0 + n16*128 + (((ks*4 + q) ^ (n16 & 7))*8));
    #pragma unroll
    for (int c2 = 0; c2 < 2; ++c2){
      int ct = 2*w + c2;
      half8 bF = *(const half8*)(W1T + (size_t)(ct*16 + n16)*128 + ks*32 + q*8);
      acc[c2] = __builtin_amdgcn_mfma_f32_16x16x32_f16(aF, bF, acc[c2], 0,0,0);
    }
  }
  // bias + silu
  float sv[2][4];
  #pragma unroll
  for (int c2=0;c2<2;++c2)
    #pragma unroll
    for (int j=0;j<4;++j){
      int col = (2*w + c2)*16 + n16;
      float v = acc[c2][j] + b1[col];
      sv[c2][j] = v / (1.f + __expf(-v));
    }
  // LN stats
  #pragma unroll
  for (int j=0;j<4;++j){
    float s  = sv[0][j] + sv[1][j];
    float sq = sv[0][j]*sv[0][j] + sv[1][j]*sv[1][j];
    #pragma unroll
    for (int m=1;m<16;m<<=1){ s += __shfl_xor(s, m, 64); sq += __shfl_xor(sq, m, 64); }
    if (n16 == 0){ sStat[(w*16 + 4*q + j)*2] = s; sStat[(w*16 + 4*q + j)*2 + 1] = sq; }
  }
  __syncthreads();
  float mu[4], rs[4];
  #pragma unroll
  for (int j=0;j<4;++j){
    int row = 4*q + j;
    float s=0.f, sq=0.f;
    #pragma unroll
    for (int w2=0;w2<4;++w2){ s += sStat[(w2*16+row)*2]; sq += sStat[(w2*16+row)*2+1]; }
    float m_ = s * (1.f/128.f);
    mu[j] = m_;
    rs[j] = rsqrtf(sq * (1.f/128.f) - m_*m_ + 1e-5f);
  }
  // h1 -> sH1
  #pragma unroll
  for (int c2=0;c2<2;++c2)
    #pragma unroll
    for (int j=0;j<4;++j){
      int col = (2*w + c2)*16 + n16;
      int row = 4*q + j;
      float hn = (sv[c2][j] - mu[j])*rs[j]*lng[col] + lnb[col];
      sH1[row*128 + (((col>>3) ^ (row&7))*8) + (col&7)] = (f16)hn;
    }
  __syncthreads();

  // ======== GEMM2: (16x128) @ W2(128x288) -> sR (f32, aliases dead phase-1 scratch) ========
  float* sR = (float*)sWk;         // [16][292] f32 = 18688 B
  f32x4 acc2[5] = {{0,0,0,0},{0,0,0,0},{0,0,0,0},{0,0,0,0},{0,0,0,0}};
  #pragma unroll
  for (int ks=0;ks<4;++ks){
    half8 aF = *(const half8*)(sH1 + n16*128 + (((ks*4 + q) ^ (n16 & 7))*8));
    #pragma unroll
    for (int t=0;t<5;++t){
      int ct = w + 4*t;
      if (ct < 18){
        half8 bF = *(const half8*)(W2T + (size_t)(ct*16 + n16)*128 + ks*32 + q*8);
        acc2[t] = __builtin_amdgcn_mfma_f32_16x16x32_f16(aF, bF, acc2[t], 0,0,0);
      }
    }
  }
  #pragma unroll
  for (int t=0;t<5;++t){
    int ct = w + 4*t;
    if (ct < 18){
      #pragma unroll
      for (int j=0;j<4;++j){
        int col = ct*16 + n16, row = 4*q + j;
        sR[row*292 + col] = acc2[t][j] + b2[col];
      }
    }
  }
  __syncthreads();

  // ======== phase 3: normalize weights, output matmuls; wave w -> its 4 edges ========
  f16* pw    = sWk + 9344 + w*1920;   // after sR's 18688 B (= 9344 f16)
  f16* LHSst = pw;                    // [32][40]
  f16* RT    = pw + 1280;             // [16][40] RHS^T
  #pragma unroll
  for (int i = 0; i < 4; ++i){
    const int le = w*4 + i;
    const int e  = e0 + le;
    // weights: lane l holds mlp_res[l*4 .. l*4+3] = matrix mm=l>>4, flat (n16*4+j)
    f32x4 w4 = *(const f32x4*)(sR + le*292 + l*4);
    float ssq = w4[0]*w4[0] + w4[1]*w4[1] + w4[2]*w4[2] + w4[3]*w4[3];
    #pragma unroll
    for (int m=1;m<16;m<<=1) ssq += __shfl_xor(ssq, m, 64);
    float rn = 1.f / (sqrtf(ssq) + 1e-6f);
    // zero RT: 640 f16 = 320 dwords = 5*64
    {
      uint32_t* z32 = (uint32_t*)RT;
      z32[l] = 0u; z32[l+64] = 0u; z32[l+128] = 0u; z32[l+192] = 0u; z32[l+256] = 0u;
    }
    const int mm = l >> 4;
    const int kk = n16 >> 1;
    #pragma unroll
    for (int j=0;j<4;++j){
      int c = (l & 1)*4 + j;
      float f = sR[le*292 + 256 + mm*8 + c];
      f16 val = (f16)(w4[j] * rn * f * 0.5f);
      int nOut = c + (mm & 1)*8;
      int rk   = kk + ((mm & 1) << 4) + ((mm >> 1) << 3);
      RT[nOut*40 + rk] = val;
    }
    // stage LHS from held registers: row d, cols 0..7 A, 8..15 Xa, 16..23 B, 24..31 Xb
    {
      int d = l >> 1, cb = (l & 1)*4;
      *(half4*)(LHSst + d*40 + cb)      = hA[i];
      *(half4*)(LHSst + d*40 + 8 + cb)  = hXa[i];
      *(half4*)(LHSst + d*40 + 16 + cb) = hB[i];
      *(half4*)(LHSst + d*40 + 24 + cb) = hXb[i];
    }
    fence_lds();
    // [out_a|out_b](32x16) = LHS(32x32) @ RHS(32x16); direct strided stores
    half8 bF = *(const half8*)(RT + n16*40 + q*8);
    f32x4 z = {0.f,0.f,0.f,0.f};
    const size_t eb = (size_t)e * 256;
    float* obase = (n16 < 8) ? (outA + eb + n16) : (outB + eb + n16 - 8);
    #pragma unroll
    for (int rt=0;rt<2;++rt){
      half8 aF = *(const half8*)(LHSst + (rt*16 + n16)*40 + q*8);
      f32x4 Dv = __builtin_amdgcn_mfma_f32_16x16x32_f16(aF, bF, z, 0,0,0);
      #pragma unroll
      for (int j=0;j<4;++j){
        int dR = rt*16 + 4*q + j;
        obase[dR*8] = Dv[j];
      }
    }
    fence_lds();
  }
}

extern "C" void kernel_launch(void* const* d_in, const int* in_sizes, int n_in,
                              void* d_out, int out_size, void* d_ws, size_t ws_size,
                              hipStream_t stream) {
  const float* x   = (const float*)d_in[0];
  const int*   ei  = (const int*)  d_in[1];
  const float* efa = (const float*)d_in[2];
  const float* efb = (const float*)d_in[3];
  const float* em  = (const float*)d_in[4];
  const float* W1  = (const float*)d_in[5];
  const float* b1  = (const float*)d_in[6];
  const float* lng = (const float*)d_in[7];
  const float* lnb = (const float*)d_in[8];
  const float* W2  = (const float*)d_in[9];
  const float* b2  = (const float*)d_in[10];
  const int E = in_sizes[1] / 2;

  float* outA = (float*)d_out;
  float* outB = outA + (size_t)E*256;
  f16* W1T = (f16*)d_ws;             // 128*128 f16
  f16* W2T = W1T + 128*128;          // 288*128 f16

  k0_convert<<<208, 256, 0, stream>>>(W1, W2, W1T, W2T);
  k_fused<<<E/16, 256, 0, stream>>>(x, ei, efa, efb, em, W1T, W2T,
                                    b1, lng, lnb, b2, outA, outB, E);
}